// Round 9
// baseline (293.661 us; speedup 1.0000x reference)
//
#include <hip/hip_runtime.h>
#include <hip/hip_bf16.h>

// B=2, T=2048, C=1024, H=16, D=64, WINDOW=512. fp32 in/out, bf16 MFMA inside.
// R20: qkv = R18's verified BK=32 staging (16KiB LDS, VGPR<=128 pinned via
// launch_bounds(256,4) -- R19's VGPR=140 crossed the 128 wave-occupancy
// cliff: 10.4% occ, 57.8us) + R19's correctness-verified operand-swap
// epilogue for qk blocks (mfma(bfr,af): N on quad*4+r, token on c16 ->
// ushort4-packed qkb stores, 16x8B vs 64x2B per thread).
// attn/prep/proj byte-identical to R18 (92.43us best).

typedef __bf16 bf16x8 __attribute__((ext_vector_type(8)));
typedef float f32x4 __attribute__((ext_vector_type(4)));

__device__ __forceinline__ unsigned short f2b(float f) {
  unsigned int u = __float_as_uint(f);
  unsigned int r = (u + 0x7FFFu + ((u >> 16) & 1u)) >> 16;
  return (unsigned short)r;
}
__device__ __forceinline__ void async16(const unsigned short* g,
                                        unsigned short* l) {
  __builtin_amdgcn_global_load_lds(
      (const __attribute__((address_space(1))) unsigned int*)g,
      (__attribute__((address_space(3))) unsigned int*)l, 16, 0, 0);
}

// -------- prep: z=0 cvt x -> xb; z=1/2 transpose+cvt w_attn/w_proj ---------
__global__ __launch_bounds__(256) void prep(
    const float* __restrict__ x, const float* __restrict__ w_attn,
    const float* __restrict__ w_proj, unsigned short* __restrict__ xb,
    unsigned short* __restrict__ wT, unsigned short* __restrict__ pT) {
  __shared__ unsigned short tile[32][33];
  const int z = blockIdx.z;
  if (z == 0) {
    const int id = blockIdx.y * 96 + blockIdx.x;
    if (id >= 2048) return;
    const int i = id * 256 + threadIdx.x;
    const float4 a = ((const float4*)x)[i * 2];
    const float4 b = ((const float4*)x)[i * 2 + 1];
    union { unsigned short us[8]; uint4 v; } t;
    t.us[0] = f2b(a.x); t.us[1] = f2b(a.y); t.us[2] = f2b(a.z); t.us[3] = f2b(a.w);
    t.us[4] = f2b(b.x); t.us[5] = f2b(b.y); t.us[6] = f2b(b.z); t.us[7] = f2b(b.w);
    ((uint4*)xb)[i] = t.v;
    return;
  }
  const float* in = (z == 1) ? w_attn : w_proj;
  unsigned short* out = (z == 1) ? wT : pT;
  const int R = 1024, Cc = (z == 1) ? 3072 : 1024;
  if (blockIdx.x * 32 >= Cc) return;
  const int t = threadIdx.x;
  const int tx = t & 31, ty0 = t >> 5;
  const int c0 = blockIdx.x * 32, r0 = blockIdx.y * 32;
  // Q-weight columns (0..1023 of w_attn) carry the softmax scale so attn's
  // inner loop needs no per-score multiply: 0.125 * log2(e) = 0.18033688.
  const float sc = (z == 1 && (c0 + tx) < 1024) ? 0.18033688f : 1.0f;
  #pragma unroll
  for (int rr = 0; rr < 32; rr += 8)
    tile[ty0 + rr][tx] = f2b(in[(size_t)(r0 + ty0 + rr) * Cc + c0 + tx] * sc);
  __syncthreads();
  #pragma unroll
  for (int rr = 0; rr < 32; rr += 8)
    out[(size_t)(c0 + ty0 + rr) * R + r0 + tx] = tile[tx][ty0 + rr];
}

// -------- qkv GEMM: BK=32 m97 + XOR-4 swizzle + XCD-rectangle map ----------
// Tile grid 32m x 24n partitioned into 8 rectangles (8m x 12n); XCD id%8
// owns one rectangle -> per-XCD L2 footprint 5MB. Block-uniform operand
// order: qk blocks (n0<2048) compute mfma(bfr,af) so N sits on quad*4+r ->
// ushort4-packed qkb stores (verified R19). v blocks keep (af,bfr)+vtb pack.
__global__ __launch_bounds__(256, 4) void gemm_qkv(
    const unsigned short* __restrict__ A, const unsigned short* __restrict__ Bt,
    unsigned short* __restrict__ qkb, unsigned short* __restrict__ vtb) {
  const int K = 1024;
  __shared__ unsigned short As[128 * 32];
  __shared__ unsigned short Bs[128 * 32];
  const int tid = threadIdx.x;
  const int w = tid >> 6, lane = tid & 63;
  const int quad = lane >> 4, c16 = lane & 15;
  const int id = blockIdx.x + 24 * blockIdx.y;   // 0..767
  const int xcd = id & 7, j = id >> 3;           // j: 0..95
  const int mt = (xcd & 3) * 8 + (j & 7);        // 0..31
  const int nt = (xcd >> 2) * 12 + (j >> 3);     // 0..23
  const int m0 = mt * 128, n0 = nt * 128;
  const bool isv = (n0 >= 2048);                 // block-uniform
  const int wm = (w & 1) * 64, wn = (w >> 1) * 64;
  const int srow = w * 16 + (lane >> 2);
  const int scol = ((lane & 3) ^ ((lane >> 2) & 3)) * 8;  // XOR-4 swizzle
  const unsigned short* ag0 = A + (size_t)(m0 + srow) * K + scol;
  const unsigned short* ag1 = A + (size_t)(m0 + 64 + srow) * K + scol;
  const unsigned short* bg0 = Bt + (size_t)(n0 + srow) * K + scol;
  const unsigned short* bg1 = Bt + (size_t)(n0 + 64 + srow) * K + scol;
  const int gsw = (quad ^ (c16 & 3)) * 8;                 // frag-read group
  f32x4 acc[4][4] = {};
  for (int k0 = 0; k0 < K; k0 += 32) {
    async16(ag0 + k0, &As[w * 512]);
    async16(ag1 + k0, &As[w * 512 + 2048]);
    async16(bg0 + k0, &Bs[w * 512]);
    async16(bg1 + k0, &Bs[w * 512 + 2048]);
    __syncthreads();
    bf16x8 af[4], bfr[4];
    #pragma unroll
    for (int mi = 0; mi < 4; ++mi)
      af[mi] = *(const bf16x8*)&As[(wm + mi * 16 + c16) * 32 + gsw];
    #pragma unroll
    for (int ni = 0; ni < 4; ++ni)
      bfr[ni] = *(const bf16x8*)&Bs[(wn + ni * 16 + c16) * 32 + gsw];
    if (!isv) {
      #pragma unroll
      for (int i = 0; i < 4; ++i)
        #pragma unroll
        for (int jj = 0; jj < 4; ++jj)
          acc[i][jj] = __builtin_amdgcn_mfma_f32_16x16x32_bf16(
              bfr[i], af[jj], acc[i][jj], 0, 0, 0);
    } else {
      #pragma unroll
      for (int i = 0; i < 4; ++i)
        #pragma unroll
        for (int jj = 0; jj < 4; ++jj)
          acc[i][jj] = __builtin_amdgcn_mfma_f32_16x16x32_bf16(
              af[i], bfr[jj], acc[i][jj], 0, 0, 0);
    }
    __syncthreads();
  }
  if (!isv) {
    // acc[i][jj]: N = n0+wn+i*16+quad*4+r, token = m0+wm+jj*16+c16
    #pragma unroll
    for (int i = 0; i < 4; ++i) {
      const int col = n0 + wn + i * 16 + quad * 4;
      #pragma unroll
      for (int jj = 0; jj < 4; ++jj) {
        const int token = m0 + wm + jj * 16 + c16;
        ushort4 pk;
        pk.x = f2b(acc[i][jj][0]); pk.y = f2b(acc[i][jj][1]);
        pk.z = f2b(acc[i][jj][2]); pk.w = f2b(acc[i][jj][3]);
        *(ushort4*)(qkb + (size_t)token * 2048 + col) = pk;
      }
    }
  } else {
    // acc[i][jj]: token base = m0+wm+i*16+quad*4 (+r), d = n0+wn+jj*16+c16-2048
    #pragma unroll
    for (int i = 0; i < 4; ++i) {
      const int rbase = m0 + wm + i * 16 + quad * 4;
      const int bidx = rbase >> 11;
      const int t0 = rbase & 2047;
      #pragma unroll
      for (int jj = 0; jj < 4; ++jj) {
        const int d = n0 + wn + jj * 16 + c16 - 2048;
        const int hh = d >> 6, dd = d & 63;
        ushort4 pk;
        pk.x = f2b(acc[i][jj][0]); pk.y = f2b(acc[i][jj][1]);
        pk.z = f2b(acc[i][jj][2]); pk.w = f2b(acc[i][jj][3]);
        *(ushort4*)(vtb + (size_t)((bidx * 16 + hh) * 64 + dd) * 2048 + t0) = pk;
      }
    }
  }
}

// -------- proj GEMM: 128x64 tiles, BK=64, XOR swizzle (R8/R9 form) ---------
__global__ __launch_bounds__(256) void gemm_proj(
    const unsigned short* __restrict__ A, const unsigned short* __restrict__ Bt,
    float* __restrict__ C, int M, int N, int K) {
  __shared__ unsigned short As[128 * 64];
  __shared__ unsigned short Bs[64 * 64];
  const int tid = threadIdx.x;
  const int w = tid >> 6, lane = tid & 63;
  const int quad = lane >> 4, c16 = lane & 15;
  const int c7 = c16 & 7;
  const int m0 = blockIdx.y * 128, n0 = blockIdx.x * 64;
  const int wm = (w & 1) * 64, wn = (w >> 1) * 32;
  const int lrow = lane >> 3;
  const int cg = (lane & 7) ^ lrow;
  const unsigned short* ag = A + (size_t)(m0 + w * 32 + lrow) * K + cg * 8;
  const unsigned short* bg = Bt + (size_t)(n0 + w * 16 + lrow) * K + cg * 8;
  f32x4 acc[4][2] = {};
  for (int k0 = 0; k0 < K; k0 += 64) {
    #pragma unroll
    for (int rnd = 0; rnd < 4; ++rnd)
      async16(ag + (size_t)rnd * 8 * K + k0, &As[(w * 32 + rnd * 8) * 64]);
    #pragma unroll
    for (int rnd = 0; rnd < 2; ++rnd)
      async16(bg + (size_t)rnd * 8 * K + k0, &Bs[(w * 16 + rnd * 8) * 64]);
    __syncthreads();
    #pragma unroll
    for (int ks = 0; ks < 2; ++ks) {
      const int gsw = ((ks * 4 + quad) ^ c7) * 8;
      bf16x8 af[4], bfr[2];
      #pragma unroll
      for (int mi = 0; mi < 4; ++mi)
        af[mi] = *(const bf16x8*)&As[(wm + mi * 16 + c16) * 64 + gsw];
      #pragma unroll
      for (int ni = 0; ni < 2; ++ni)
        bfr[ni] = *(const bf16x8*)&Bs[(wn + ni * 16 + c16) * 64 + gsw];
      #pragma unroll
      for (int mi = 0; mi < 4; ++mi)
        #pragma unroll
        for (int ni = 0; ni < 2; ++ni)
          acc[mi][ni] = __builtin_amdgcn_mfma_f32_16x16x32_bf16(
              af[mi], bfr[ni], acc[mi][ni], 0, 0, 0);
    }
    __syncthreads();
  }
  #pragma unroll
  for (int mi = 0; mi < 4; ++mi)
    #pragma unroll
    for (int ni = 0; ni < 2; ++ni) {
      const int colC = n0 + wn + ni * 16 + c16;
      const int rbase = m0 + wm + mi * 16 + quad * 4;
      #pragma unroll
      for (int r = 0; r < 4; ++r)
        C[(size_t)(rbase + r) * N + colC] = acc[mi][ni][r];
    }
}

// -------- flash attention, S^T form, 16 q/wave, 64-q blocks, staged --------
// Grid 1024 blocks (4/CU, LDS exactly 40960B). id&7 = XCD; each XCD owns
// 4 heads x all 32 q-tiles -> per-XCD K/V 2MB (L2-resident re-reads).
__global__ __launch_bounds__(256) void attn_flash(
    const unsigned short* __restrict__ qk,   // [4096][2048]
    const unsigned short* __restrict__ vtg,  // [(b*16+h)*64+d][2048]
    unsigned short* __restrict__ y) {        // [4096][1024]
  __shared__ unsigned short Ks[2][64 * 64];
  __shared__ unsigned short Vs[2][64 * 64];
  __shared__ unsigned short Pt[64 * 64];     // octet-XOR swizzled
  const int tid = threadIdx.x;
  const int w = tid >> 6, lane = tid & 63;
  const int quad = lane >> 4, c16 = lane & 15;
  const int c7 = c16 & 7;
  // XCD head-cluster swizzle: flat id -> (xcd owns heads xcd*4..xcd*4+3)
  const int id = blockIdx.x + 32 * blockIdx.y;   // 0..1023
  const int xcd = id & 7, jj = id >> 3;          // jj: 0..127
  const int by = xcd * 4 + (jj >> 5);            // (b,h) 0..31
  const int bx = jj & 31;                        // q-tile
  const int b = by >> 4, h = by & 15;
  const int i0 = bx * 64;
  const int q0 = i0 + w * 16;                    // wave's 16 q-rows

  bf16x8 qb[2];
  {
    const size_t qr = (size_t)(b * 2048 + q0 + c16) * 2048 + h * 64;
    qb[0] = *(const bf16x8*)(qk + qr + quad * 8);
    qb[1] = *(const bf16x8*)(qk + qr + 32 + quad * 8);
  }
  // ones fragment for the lsum MFMA
  bf16x8 onesf;
  #pragma unroll
  for (int i = 0; i < 8; ++i) onesf[i] = (__bf16)1.0f;

  const int lrow = lane >> 3;
  const int cg = (lane & 7) ^ lrow;
  const int row0 = w * 16 + lrow;
  const int t_start = (i0 >= 512) ? ((i0 - 511) >> 6) : 0;
  const int t_end = (i0 + 63) >> 6;

  const unsigned short* kp0 =
      qk + (size_t)(b * 2048 + t_start * 64 + row0) * 2048 + 1024 + h * 64 + cg * 8;
  const unsigned short* kp1 = kp0 + (size_t)8 * 2048;
  const unsigned short* vp0 =
      vtg + (size_t)((b * 16 + h) * 64 + row0) * 2048 + t_start * 64 + cg * 8;
  const unsigned short* vp1 = vp0 + (size_t)8 * 2048;

  async16(kp0, &Ks[0][(w * 16) * 64]);
  async16(kp1, &Ks[0][(w * 16 + 8) * 64]);
  async16(vp0, &Vs[0][(w * 16) * 64]);
  async16(vp1, &Vs[0][(w * 16 + 8) * 64]);
  kp0 += 131072; kp1 += 131072; vp0 += 64; vp1 += 64;
  __syncthreads();

  f32x4 o[4] = {};
  f32x4 ls = {};
  int cur = 0;

  for (int t = t_start; t <= t_end; ++t) {
    if (t < t_end) {
      unsigned short* kb = &Ks[cur ^ 1][0];
      unsigned short* vb = &Vs[cur ^ 1][0];
      async16(kp0, kb + (w * 16) * 64);
      async16(kp1, kb + (w * 16 + 8) * 64);
      async16(vp0, vb + (w * 16) * 64);
      async16(vp1, vb + (w * 16 + 8) * 64);
      kp0 += 131072; kp1 += 131072; vp0 += 64; vp1 += 64;
    }
    const int kbase = t * 64;
    if (kbase <= q0 + 15 && kbase + 63 >= q0 - 511) {
      const unsigned short* Kc = &Ks[cur][0];
      const unsigned short* Vc = &Vs[cur][0];

      f32x4 s[4] = {};
      #pragma unroll
      for (int nb = 0; nb < 4; ++nb) {
        const int row = nb * 16 + c16;
        bf16x8 a0 = *(const bf16x8*)&Kc[row * 64 + (quad ^ c7) * 8];
        bf16x8 a1 = *(const bf16x8*)&Kc[row * 64 + ((quad + 4) ^ c7) * 8];
        s[nb] = __builtin_amdgcn_mfma_f32_16x16x32_bf16(a0, qb[0], s[nb], 0, 0, 0);
        s[nb] = __builtin_amdgcn_mfma_f32_16x16x32_bf16(a1, qb[1], s[nb], 0, 0, 0);
      }

      const bool full = (kbase + 63 <= q0) && (kbase >= q0 - 496);
      const int iq = q0 + c16;
      const int prow = w * 16 + c16;
      #pragma unroll
      for (int nb = 0; nb < 4; ++nb) {
        ushort4 pk;
        unsigned short* pks = (unsigned short*)&pk;
        #pragma unroll
        for (int r = 0; r < 4; ++r) {
          // scores arrive pre-scaled by 0.125*log2(e) (folded into Q wts)
          float sv = s[nb][r];
          if (!full) {
            const int j = kbase + nb * 16 + quad * 4 + r;
            const bool valid = (j <= iq) && (j >= iq - 511);
            sv = valid ? sv : -3.0e38f;
          }
          const unsigned int pu = __float_as_uint(exp2f(sv)) & 0xffff0000u;
          pks[r] = (unsigned short)(pu >> 16);
        }
        // write octet nb*2+(quad>>1), XOR row&7; 8B half (quad&1)
        *(ushort4*)&Pt[prow * 64 + (((nb * 2 + (quad >> 1)) ^ c7) * 8) +
                       (quad & 1) * 4] = pk;
      }

      #pragma unroll
      for (int ks2 = 0; ks2 < 2; ++ks2) {
        bf16x8 pb = *(const bf16x8*)&Pt[prow * 64 + (((ks2 * 4 + quad) ^ c7) * 8)];
        ls = __builtin_amdgcn_mfma_f32_16x16x32_bf16(onesf, pb, ls, 0, 0, 0);
        #pragma unroll
        for (int nb = 0; nb < 4; ++nb) {
          const int row = nb * 16 + c16;
          bf16x8 va = *(const bf16x8*)&Vc[row * 64 + ((quad + 4 * ks2) ^ c7) * 8];
          o[nb] = __builtin_amdgcn_mfma_f32_16x16x32_bf16(va, pb, o[nb], 0, 0, 0);
        }
      }
    }
    __syncthreads();
    cur ^= 1;
  }

  // ls[r] = sum_k P[k][q=c16] for every r/quad (ones x P) -> no shuffle
  const float inv = 1.0f / ls[0];
  const int iq = q0 + c16;
  #pragma unroll
  for (int nb = 0; nb < 4; ++nb) {
    ushort4 pk;
    unsigned short* pks = (unsigned short*)&pk;
    #pragma unroll
    for (int r = 0; r < 4; ++r) pks[r] = f2b(o[nb][r] * inv);
    *(ushort4*)(y + (size_t)(b * 2048 + iq) * 1024 + h * 64 + nb * 16 + quad * 4) = pk;
  }
}

// ---------------------------------------------------------------------------
extern "C" void kernel_launch(void* const* d_in, const int* in_sizes, int n_in,
                              void* d_out, int out_size, void* d_ws, size_t ws_size,
                              hipStream_t stream) {
  const float* x      = (const float*)d_in[0];  // [4096,1024] fp32
  const float* w_attn = (const float*)d_in[1];  // [1024,3072] fp32
  const float* w_proj = (const float*)d_in[2];  // [1024,1024] fp32
  float* out = (float*)d_out;                   // [4096,1024] fp32

  // ws (bf16 elems): qkb 8M | vtb 4M | wT 3M | pT 1M | xb/y 4M  = 40MB
  unsigned short* qkb = (unsigned short*)d_ws;        // [4096][2048]
  unsigned short* vtb = qkb + (size_t)4096 * 2048;    // [2048][2048]
  unsigned short* wT  = vtb + (size_t)2048 * 2048;    // [3072][1024]
  unsigned short* pT  = wT + (size_t)3072 * 1024;     // [1024][1024]
  unsigned short* xb  = pT + (size_t)1024 * 1024;     // [4096][1024]
  unsigned short* y   = xb;                           // reuse (xb dead post-GEMM1)

  prep<<<dim3(96, 32, 3), 256, 0, stream>>>(x, w_attn, w_proj, xb, wT, pT);

  gemm_qkv<<<dim3(24, 32), 256, 0, stream>>>(xb, wT, qkb, vtb);

  attn_flash<<<dim3(32, 32), 256, 0, stream>>>(qkb, vtb, y);

  gemm_proj<<<dim3(1024 / 64, 4096 / 128), 256, 0, stream>>>(
      y, pT, out, 4096, 1024, 1024);
}

// Round 10
// 123.865 us; speedup vs baseline: 2.3708x; 2.3708x over previous
//
#include <hip/hip_runtime.h>
#include <hip/hip_bf16.h>

// B=2, T=2048, C=1024, H=16, D=64, WINDOW=512. fp32 in/out, bf16 MFMA inside.
// R21: R20's launch_bounds(256,4) REMOVED -- the 2nd arg is min waves/EU,
// not blocks/CU; it forced VGPR=64 -> mass spill (739MB scratch writes,
// 258us). Back to R18's plain launch_bounds(256) allocator freedom.
// Kept: R19/R20 correctness-verified operand-swap epilogue for qk blocks
// (mfma(bfr,af): N on quad*4+r, token on c16 -> ushort4-packed qkb stores).
// attn/prep/proj byte-identical to R18 (92.43us best).

typedef __bf16 bf16x8 __attribute__((ext_vector_type(8)));
typedef float f32x4 __attribute__((ext_vector_type(4)));

__device__ __forceinline__ unsigned short f2b(float f) {
  unsigned int u = __float_as_uint(f);
  unsigned int r = (u + 0x7FFFu + ((u >> 16) & 1u)) >> 16;
  return (unsigned short)r;
}
__device__ __forceinline__ void async16(const unsigned short* g,
                                        unsigned short* l) {
  __builtin_amdgcn_global_load_lds(
      (const __attribute__((address_space(1))) unsigned int*)g,
      (__attribute__((address_space(3))) unsigned int*)l, 16, 0, 0);
}

// -------- prep: z=0 cvt x -> xb; z=1/2 transpose+cvt w_attn/w_proj ---------
__global__ __launch_bounds__(256) void prep(
    const float* __restrict__ x, const float* __restrict__ w_attn,
    const float* __restrict__ w_proj, unsigned short* __restrict__ xb,
    unsigned short* __restrict__ wT, unsigned short* __restrict__ pT) {
  __shared__ unsigned short tile[32][33];
  const int z = blockIdx.z;
  if (z == 0) {
    const int id = blockIdx.y * 96 + blockIdx.x;
    if (id >= 2048) return;
    const int i = id * 256 + threadIdx.x;
    const float4 a = ((const float4*)x)[i * 2];
    const float4 b = ((const float4*)x)[i * 2 + 1];
    union { unsigned short us[8]; uint4 v; } t;
    t.us[0] = f2b(a.x); t.us[1] = f2b(a.y); t.us[2] = f2b(a.z); t.us[3] = f2b(a.w);
    t.us[4] = f2b(b.x); t.us[5] = f2b(b.y); t.us[6] = f2b(b.z); t.us[7] = f2b(b.w);
    ((uint4*)xb)[i] = t.v;
    return;
  }
  const float* in = (z == 1) ? w_attn : w_proj;
  unsigned short* out = (z == 1) ? wT : pT;
  const int R = 1024, Cc = (z == 1) ? 3072 : 1024;
  if (blockIdx.x * 32 >= Cc) return;
  const int t = threadIdx.x;
  const int tx = t & 31, ty0 = t >> 5;
  const int c0 = blockIdx.x * 32, r0 = blockIdx.y * 32;
  // Q-weight columns (0..1023 of w_attn) carry the softmax scale so attn's
  // inner loop needs no per-score multiply: 0.125 * log2(e) = 0.18033688.
  const float sc = (z == 1 && (c0 + tx) < 1024) ? 0.18033688f : 1.0f;
  #pragma unroll
  for (int rr = 0; rr < 32; rr += 8)
    tile[ty0 + rr][tx] = f2b(in[(size_t)(r0 + ty0 + rr) * Cc + c0 + tx] * sc);
  __syncthreads();
  #pragma unroll
  for (int rr = 0; rr < 32; rr += 8)
    out[(size_t)(c0 + ty0 + rr) * R + r0 + tx] = tile[tx][ty0 + rr];
}

// -------- qkv GEMM: BK=32 m97 + XOR-4 swizzle + XCD-rectangle map ----------
// Tile grid 32m x 24n partitioned into 8 rectangles (8m x 12n); XCD id%8
// owns one rectangle -> per-XCD L2 footprint 5MB. Block-uniform operand
// order: qk blocks (n0<2048) compute mfma(bfr,af) so N sits on quad*4+r ->
// ushort4-packed qkb stores (verified R19/R20). v blocks keep (af,bfr).
__global__ __launch_bounds__(256) void gemm_qkv(
    const unsigned short* __restrict__ A, const unsigned short* __restrict__ Bt,
    unsigned short* __restrict__ qkb, unsigned short* __restrict__ vtb) {
  const int K = 1024;
  __shared__ unsigned short As[128 * 32];
  __shared__ unsigned short Bs[128 * 32];
  const int tid = threadIdx.x;
  const int w = tid >> 6, lane = tid & 63;
  const int quad = lane >> 4, c16 = lane & 15;
  const int id = blockIdx.x + 24 * blockIdx.y;   // 0..767
  const int xcd = id & 7, j = id >> 3;           // j: 0..95
  const int mt = (xcd & 3) * 8 + (j & 7);        // 0..31
  const int nt = (xcd >> 2) * 12 + (j >> 3);     // 0..23
  const int m0 = mt * 128, n0 = nt * 128;
  const bool isv = (n0 >= 2048);                 // block-uniform
  const int wm = (w & 1) * 64, wn = (w >> 1) * 64;
  const int srow = w * 16 + (lane >> 2);
  const int scol = ((lane & 3) ^ ((lane >> 2) & 3)) * 8;  // XOR-4 swizzle
  const unsigned short* ag0 = A + (size_t)(m0 + srow) * K + scol;
  const unsigned short* ag1 = A + (size_t)(m0 + 64 + srow) * K + scol;
  const unsigned short* bg0 = Bt + (size_t)(n0 + srow) * K + scol;
  const unsigned short* bg1 = Bt + (size_t)(n0 + 64 + srow) * K + scol;
  const int gsw = (quad ^ (c16 & 3)) * 8;                 // frag-read group
  f32x4 acc[4][4] = {};
  for (int k0 = 0; k0 < K; k0 += 32) {
    async16(ag0 + k0, &As[w * 512]);
    async16(ag1 + k0, &As[w * 512 + 2048]);
    async16(bg0 + k0, &Bs[w * 512]);
    async16(bg1 + k0, &Bs[w * 512 + 2048]);
    __syncthreads();
    bf16x8 af[4], bfr[4];
    #pragma unroll
    for (int mi = 0; mi < 4; ++mi)
      af[mi] = *(const bf16x8*)&As[(wm + mi * 16 + c16) * 32 + gsw];
    #pragma unroll
    for (int ni = 0; ni < 4; ++ni)
      bfr[ni] = *(const bf16x8*)&Bs[(wn + ni * 16 + c16) * 32 + gsw];
    if (!isv) {
      #pragma unroll
      for (int i = 0; i < 4; ++i)
        #pragma unroll
        for (int jj = 0; jj < 4; ++jj)
          acc[i][jj] = __builtin_amdgcn_mfma_f32_16x16x32_bf16(
              bfr[i], af[jj], acc[i][jj], 0, 0, 0);
    } else {
      #pragma unroll
      for (int i = 0; i < 4; ++i)
        #pragma unroll
        for (int jj = 0; jj < 4; ++jj)
          acc[i][jj] = __builtin_amdgcn_mfma_f32_16x16x32_bf16(
              af[i], bfr[jj], acc[i][jj], 0, 0, 0);
    }
    __syncthreads();
  }
  if (!isv) {
    // acc[i][jj]: N = n0+wn+i*16+quad*4+r, token = m0+wm+jj*16+c16
    #pragma unroll
    for (int i = 0; i < 4; ++i) {
      const int col = n0 + wn + i * 16 + quad * 4;
      #pragma unroll
      for (int jj = 0; jj < 4; ++jj) {
        const int token = m0 + wm + jj * 16 + c16;
        ushort4 pk;
        pk.x = f2b(acc[i][jj][0]); pk.y = f2b(acc[i][jj][1]);
        pk.z = f2b(acc[i][jj][2]); pk.w = f2b(acc[i][jj][3]);
        *(ushort4*)(qkb + (size_t)token * 2048 + col) = pk;
      }
    }
  } else {
    // acc[i][jj]: token base = m0+wm+i*16+quad*4 (+r), d = n0+wn+jj*16+c16-2048
    #pragma unroll
    for (int i = 0; i < 4; ++i) {
      const int rbase = m0 + wm + i * 16 + quad * 4;
      const int bidx = rbase >> 11;
      const int t0 = rbase & 2047;
      #pragma unroll
      for (int jj = 0; jj < 4; ++jj) {
        const int d = n0 + wn + jj * 16 + c16 - 2048;
        const int hh = d >> 6, dd = d & 63;
        ushort4 pk;
        pk.x = f2b(acc[i][jj][0]); pk.y = f2b(acc[i][jj][1]);
        pk.z = f2b(acc[i][jj][2]); pk.w = f2b(acc[i][jj][3]);
        *(ushort4*)(vtb + (size_t)((bidx * 16 + hh) * 64 + dd) * 2048 + t0) = pk;
      }
    }
  }
}

// -------- proj GEMM: 128x64 tiles, BK=64, XOR swizzle (R8/R9 form) ---------
__global__ __launch_bounds__(256) void gemm_proj(
    const unsigned short* __restrict__ A, const unsigned short* __restrict__ Bt,
    float* __restrict__ C, int M, int N, int K) {
  __shared__ unsigned short As[128 * 64];
  __shared__ unsigned short Bs[64 * 64];
  const int tid = threadIdx.x;
  const int w = tid >> 6, lane = tid & 63;
  const int quad = lane >> 4, c16 = lane & 15;
  const int c7 = c16 & 7;
  const int m0 = blockIdx.y * 128, n0 = blockIdx.x * 64;
  const int wm = (w & 1) * 64, wn = (w >> 1) * 32;
  const int lrow = lane >> 3;
  const int cg = (lane & 7) ^ lrow;
  const unsigned short* ag = A + (size_t)(m0 + w * 32 + lrow) * K + cg * 8;
  const unsigned short* bg = Bt + (size_t)(n0 + w * 16 + lrow) * K + cg * 8;
  f32x4 acc[4][2] = {};
  for (int k0 = 0; k0 < K; k0 += 64) {
    #pragma unroll
    for (int rnd = 0; rnd < 4; ++rnd)
      async16(ag + (size_t)rnd * 8 * K + k0, &As[(w * 32 + rnd * 8) * 64]);
    #pragma unroll
    for (int rnd = 0; rnd < 2; ++rnd)
      async16(bg + (size_t)rnd * 8 * K + k0, &Bs[(w * 16 + rnd * 8) * 64]);
    __syncthreads();
    #pragma unroll
    for (int ks = 0; ks < 2; ++ks) {
      const int gsw = ((ks * 4 + quad) ^ c7) * 8;
      bf16x8 af[4], bfr[2];
      #pragma unroll
      for (int mi = 0; mi < 4; ++mi)
        af[mi] = *(const bf16x8*)&As[(wm + mi * 16 + c16) * 64 + gsw];
      #pragma unroll
      for (int ni = 0; ni < 2; ++ni)
        bfr[ni] = *(const bf16x8*)&Bs[(wn + ni * 16 + c16) * 64 + gsw];
      #pragma unroll
      for (int mi = 0; mi < 4; ++mi)
        #pragma unroll
        for (int ni = 0; ni < 2; ++ni)
          acc[mi][ni] = __builtin_amdgcn_mfma_f32_16x16x32_bf16(
              af[mi], bfr[ni], acc[mi][ni], 0, 0, 0);
    }
    __syncthreads();
  }
  #pragma unroll
  for (int mi = 0; mi < 4; ++mi)
    #pragma unroll
    for (int ni = 0; ni < 2; ++ni) {
      const int colC = n0 + wn + ni * 16 + c16;
      const int rbase = m0 + wm + mi * 16 + quad * 4;
      #pragma unroll
      for (int r = 0; r < 4; ++r)
        C[(size_t)(rbase + r) * N + colC] = acc[mi][ni][r];
    }
}

// -------- flash attention, S^T form, 16 q/wave, 64-q blocks, staged --------
// Grid 1024 blocks (4/CU, LDS exactly 40960B). id&7 = XCD; each XCD owns
// 4 heads x all 32 q-tiles -> per-XCD K/V 2MB (L2-resident re-reads).
__global__ __launch_bounds__(256) void attn_flash(
    const unsigned short* __restrict__ qk,   // [4096][2048]
    const unsigned short* __restrict__ vtg,  // [(b*16+h)*64+d][2048]
    unsigned short* __restrict__ y) {        // [4096][1024]
  __shared__ unsigned short Ks[2][64 * 64];
  __shared__ unsigned short Vs[2][64 * 64];
  __shared__ unsigned short Pt[64 * 64];     // octet-XOR swizzled
  const int tid = threadIdx.x;
  const int w = tid >> 6, lane = tid & 63;
  const int quad = lane >> 4, c16 = lane & 15;
  const int c7 = c16 & 7;
  // XCD head-cluster swizzle: flat id -> (xcd owns heads xcd*4..xcd*4+3)
  const int id = blockIdx.x + 32 * blockIdx.y;   // 0..1023
  const int xcd = id & 7, jj = id >> 3;          // jj: 0..127
  const int by = xcd * 4 + (jj >> 5);            // (b,h) 0..31
  const int bx = jj & 31;                        // q-tile
  const int b = by >> 4, h = by & 15;
  const int i0 = bx * 64;
  const int q0 = i0 + w * 16;                    // wave's 16 q-rows

  bf16x8 qb[2];
  {
    const size_t qr = (size_t)(b * 2048 + q0 + c16) * 2048 + h * 64;
    qb[0] = *(const bf16x8*)(qk + qr + quad * 8);
    qb[1] = *(const bf16x8*)(qk + qr + 32 + quad * 8);
  }
  // ones fragment for the lsum MFMA
  bf16x8 onesf;
  #pragma unroll
  for (int i = 0; i < 8; ++i) onesf[i] = (__bf16)1.0f;

  const int lrow = lane >> 3;
  const int cg = (lane & 7) ^ lrow;
  const int row0 = w * 16 + lrow;
  const int t_start = (i0 >= 512) ? ((i0 - 511) >> 6) : 0;
  const int t_end = (i0 + 63) >> 6;

  const unsigned short* kp0 =
      qk + (size_t)(b * 2048 + t_start * 64 + row0) * 2048 + 1024 + h * 64 + cg * 8;
  const unsigned short* kp1 = kp0 + (size_t)8 * 2048;
  const unsigned short* vp0 =
      vtg + (size_t)((b * 16 + h) * 64 + row0) * 2048 + t_start * 64 + cg * 8;
  const unsigned short* vp1 = vp0 + (size_t)8 * 2048;

  async16(kp0, &Ks[0][(w * 16) * 64]);
  async16(kp1, &Ks[0][(w * 16 + 8) * 64]);
  async16(vp0, &Vs[0][(w * 16) * 64]);
  async16(vp1, &Vs[0][(w * 16 + 8) * 64]);
  kp0 += 131072; kp1 += 131072; vp0 += 64; vp1 += 64;
  __syncthreads();

  f32x4 o[4] = {};
  f32x4 ls = {};
  int cur = 0;

  for (int t = t_start; t <= t_end; ++t) {
    if (t < t_end) {
      unsigned short* kb = &Ks[cur ^ 1][0];
      unsigned short* vb = &Vs[cur ^ 1][0];
      async16(kp0, kb + (w * 16) * 64);
      async16(kp1, kb + (w * 16 + 8) * 64);
      async16(vp0, vb + (w * 16) * 64);
      async16(vp1, vb + (w * 16 + 8) * 64);
      kp0 += 131072; kp1 += 131072; vp0 += 64; vp1 += 64;
    }
    const int kbase = t * 64;
    if (kbase <= q0 + 15 && kbase + 63 >= q0 - 511) {
      const unsigned short* Kc = &Ks[cur][0];
      const unsigned short* Vc = &Vs[cur][0];

      f32x4 s[4] = {};
      #pragma unroll
      for (int nb = 0; nb < 4; ++nb) {
        const int row = nb * 16 + c16;
        bf16x8 a0 = *(const bf16x8*)&Kc[row * 64 + (quad ^ c7) * 8];
        bf16x8 a1 = *(const bf16x8*)&Kc[row * 64 + ((quad + 4) ^ c7) * 8];
        s[nb] = __builtin_amdgcn_mfma_f32_16x16x32_bf16(a0, qb[0], s[nb], 0, 0, 0);
        s[nb] = __builtin_amdgcn_mfma_f32_16x16x32_bf16(a1, qb[1], s[nb], 0, 0, 0);
      }

      const bool full = (kbase + 63 <= q0) && (kbase >= q0 - 496);
      const int iq = q0 + c16;
      const int prow = w * 16 + c16;
      #pragma unroll
      for (int nb = 0; nb < 4; ++nb) {
        ushort4 pk;
        unsigned short* pks = (unsigned short*)&pk;
        #pragma unroll
        for (int r = 0; r < 4; ++r) {
          // scores arrive pre-scaled by 0.125*log2(e) (folded into Q wts)
          float sv = s[nb][r];
          if (!full) {
            const int j = kbase + nb * 16 + quad * 4 + r;
            const bool valid = (j <= iq) && (j >= iq - 511);
            sv = valid ? sv : -3.0e38f;
          }
          const unsigned int pu = __float_as_uint(exp2f(sv)) & 0xffff0000u;
          pks[r] = (unsigned short)(pu >> 16);
        }
        // write octet nb*2+(quad>>1), XOR row&7; 8B half (quad&1)
        *(ushort4*)&Pt[prow * 64 + (((nb * 2 + (quad >> 1)) ^ c7) * 8) +
                       (quad & 1) * 4] = pk;
      }

      #pragma unroll
      for (int ks2 = 0; ks2 < 2; ++ks2) {
        bf16x8 pb = *(const bf16x8*)&Pt[prow * 64 + (((ks2 * 4 + quad) ^ c7) * 8)];
        ls = __builtin_amdgcn_mfma_f32_16x16x32_bf16(onesf, pb, ls, 0, 0, 0);
        #pragma unroll
        for (int nb = 0; nb < 4; ++nb) {
          const int row = nb * 16 + c16;
          bf16x8 va = *(const bf16x8*)&Vc[row * 64 + ((quad + 4 * ks2) ^ c7) * 8];
          o[nb] = __builtin_amdgcn_mfma_f32_16x16x32_bf16(va, pb, o[nb], 0, 0, 0);
        }
      }
    }
    __syncthreads();
    cur ^= 1;
  }

  // ls[r] = sum_k P[k][q=c16] for every r/quad (ones x P) -> no shuffle
  const float inv = 1.0f / ls[0];
  const int iq = q0 + c16;
  #pragma unroll
  for (int nb = 0; nb < 4; ++nb) {
    ushort4 pk;
    unsigned short* pks = (unsigned short*)&pk;
    #pragma unroll
    for (int r = 0; r < 4; ++r) pks[r] = f2b(o[nb][r] * inv);
    *(ushort4*)(y + (size_t)(b * 2048 + iq) * 1024 + h * 64 + nb * 16 + quad * 4) = pk;
  }
}

// ---------------------------------------------------------------------------
extern "C" void kernel_launch(void* const* d_in, const int* in_sizes, int n_in,
                              void* d_out, int out_size, void* d_ws, size_t ws_size,
                              hipStream_t stream) {
  const float* x      = (const float*)d_in[0];  // [4096,1024] fp32
  const float* w_attn = (const float*)d_in[1];  // [1024,3072] fp32
  const float* w_proj = (const float*)d_in[2];  // [1024,1024] fp32
  float* out = (float*)d_out;                   // [4096,1024] fp32

  // ws (bf16 elems): qkb 8M | vtb 4M | wT 3M | pT 1M | xb/y 4M  = 40MB
  unsigned short* qkb = (unsigned short*)d_ws;        // [4096][2048]
  unsigned short* vtb = qkb + (size_t)4096 * 2048;    // [2048][2048]
  unsigned short* wT  = vtb + (size_t)2048 * 2048;    // [3072][1024]
  unsigned short* pT  = wT + (size_t)3072 * 1024;     // [1024][1024]
  unsigned short* xb  = pT + (size_t)1024 * 1024;     // [4096][1024]
  unsigned short* y   = xb;                           // reuse (xb dead post-GEMM1)

  prep<<<dim3(96, 32, 3), 256, 0, stream>>>(x, w_attn, w_proj, xb, wT, pT);

  gemm_qkv<<<dim3(24, 32), 256, 0, stream>>>(xb, wT, qkb, vtb);

  attn_flash<<<dim3(32, 32), 256, 0, stream>>>(qkb, vtb, y);

  gemm_proj<<<dim3(1024 / 64, 4096 / 128), 256, 0, stream>>>(
      y, pT, out, 4096, 1024, 1024);
}

// Round 11
// 92.352 us; speedup vs baseline: 3.1798x; 1.3412x over previous
//
#include <hip/hip_runtime.h>
#include <hip/hip_bf16.h>

// B=2, T=2048, C=1024, H=16, D=64, WINDOW=512. fp32 in/out, bf16 MFMA inside.
// R22: FULL revert of gemm_qkv to the R18-verified m97 BK=32 kernel
// (VGPR=104, 0 bank conflicts, 33.5us). R19/R20/R21 all showed the
// operand-swap epilogue graft raises VGPR to 140 (occupancy cliff at 128)
// and introduces 3.1M LDS conflicts -- net large loss. qkv is a local
// optimum; stop perturbing it.
// State = R18 exactly: prep (scale-folded wT) -> gemm_qkv (BK=32) ->
// attn (16 q/wave, 64-q blocks, XCD head-cluster, ones-MFMA lsum) -> proj.

typedef __bf16 bf16x8 __attribute__((ext_vector_type(8)));
typedef float f32x4 __attribute__((ext_vector_type(4)));

__device__ __forceinline__ unsigned short f2b(float f) {
  unsigned int u = __float_as_uint(f);
  unsigned int r = (u + 0x7FFFu + ((u >> 16) & 1u)) >> 16;
  return (unsigned short)r;
}
__device__ __forceinline__ void async16(const unsigned short* g,
                                        unsigned short* l) {
  __builtin_amdgcn_global_load_lds(
      (const __attribute__((address_space(1))) unsigned int*)g,
      (__attribute__((address_space(3))) unsigned int*)l, 16, 0, 0);
}

// -------- prep: z=0 cvt x -> xb; z=1/2 transpose+cvt w_attn/w_proj ---------
__global__ __launch_bounds__(256) void prep(
    const float* __restrict__ x, const float* __restrict__ w_attn,
    const float* __restrict__ w_proj, unsigned short* __restrict__ xb,
    unsigned short* __restrict__ wT, unsigned short* __restrict__ pT) {
  __shared__ unsigned short tile[32][33];
  const int z = blockIdx.z;
  if (z == 0) {
    const int id = blockIdx.y * 96 + blockIdx.x;
    if (id >= 2048) return;
    const int i = id * 256 + threadIdx.x;
    const float4 a = ((const float4*)x)[i * 2];
    const float4 b = ((const float4*)x)[i * 2 + 1];
    union { unsigned short us[8]; uint4 v; } t;
    t.us[0] = f2b(a.x); t.us[1] = f2b(a.y); t.us[2] = f2b(a.z); t.us[3] = f2b(a.w);
    t.us[4] = f2b(b.x); t.us[5] = f2b(b.y); t.us[6] = f2b(b.z); t.us[7] = f2b(b.w);
    ((uint4*)xb)[i] = t.v;
    return;
  }
  const float* in = (z == 1) ? w_attn : w_proj;
  unsigned short* out = (z == 1) ? wT : pT;
  const int R = 1024, Cc = (z == 1) ? 3072 : 1024;
  if (blockIdx.x * 32 >= Cc) return;
  const int t = threadIdx.x;
  const int tx = t & 31, ty0 = t >> 5;
  const int c0 = blockIdx.x * 32, r0 = blockIdx.y * 32;
  // Q-weight columns (0..1023 of w_attn) carry the softmax scale so attn's
  // inner loop needs no per-score multiply: 0.125 * log2(e) = 0.18033688.
  const float sc = (z == 1 && (c0 + tx) < 1024) ? 0.18033688f : 1.0f;
  #pragma unroll
  for (int rr = 0; rr < 32; rr += 8)
    tile[ty0 + rr][tx] = f2b(in[(size_t)(r0 + ty0 + rr) * Cc + c0 + tx] * sc);
  __syncthreads();
  #pragma unroll
  for (int rr = 0; rr < 32; rr += 8)
    out[(size_t)(c0 + ty0 + rr) * R + r0 + tx] = tile[tx][ty0 + rr];
}

// -------- qkv GEMM: BK=32 m97 + XOR-4 swizzle + XCD-rectangle map ----------
// Tile grid 32m x 24n partitioned into 8 rectangles (8m x 12n); XCD id%8
// owns one rectangle -> per-XCD L2 footprint A 2MB + B 3MB = 5MB.
// R18-verified: VGPR=104, 0 conflicts, ~33.5us. DO NOT perturb the inner
// loop (R19/R20/R21: every graft crossed the 128-VGPR occupancy cliff).
__global__ __launch_bounds__(256) void gemm_qkv(
    const unsigned short* __restrict__ A, const unsigned short* __restrict__ Bt,
    unsigned short* __restrict__ qkb, unsigned short* __restrict__ vtb) {
  const int K = 1024;
  __shared__ unsigned short As[128 * 32];
  __shared__ unsigned short Bs[128 * 32];
  const int tid = threadIdx.x;
  const int w = tid >> 6, lane = tid & 63;
  const int quad = lane >> 4, c16 = lane & 15;
  const int id = blockIdx.x + 24 * blockIdx.y;   // 0..767
  const int xcd = id & 7, j = id >> 3;           // j: 0..95
  const int mt = (xcd & 3) * 8 + (j & 7);        // 0..31
  const int nt = (xcd >> 2) * 12 + (j >> 3);     // 0..23
  const int m0 = mt * 128, n0 = nt * 128;
  const int wm = (w & 1) * 64, wn = (w >> 1) * 64;
  const int srow = w * 16 + (lane >> 2);
  const int scol = ((lane & 3) ^ ((lane >> 2) & 3)) * 8;  // XOR-4 swizzle
  const unsigned short* ag0 = A + (size_t)(m0 + srow) * K + scol;
  const unsigned short* ag1 = A + (size_t)(m0 + 64 + srow) * K + scol;
  const unsigned short* bg0 = Bt + (size_t)(n0 + srow) * K + scol;
  const unsigned short* bg1 = Bt + (size_t)(n0 + 64 + srow) * K + scol;
  const int gsw = (quad ^ (c16 & 3)) * 8;                 // frag-read group
  f32x4 acc[4][4] = {};
  for (int k0 = 0; k0 < K; k0 += 32) {
    async16(ag0 + k0, &As[w * 512]);
    async16(ag1 + k0, &As[w * 512 + 2048]);
    async16(bg0 + k0, &Bs[w * 512]);
    async16(bg1 + k0, &Bs[w * 512 + 2048]);
    __syncthreads();
    bf16x8 af[4], bfr[4];
    #pragma unroll
    for (int mi = 0; mi < 4; ++mi)
      af[mi] = *(const bf16x8*)&As[(wm + mi * 16 + c16) * 32 + gsw];
    #pragma unroll
    for (int ni = 0; ni < 4; ++ni)
      bfr[ni] = *(const bf16x8*)&Bs[(wn + ni * 16 + c16) * 32 + gsw];
    #pragma unroll
    for (int mi = 0; mi < 4; ++mi)
      #pragma unroll
      for (int ni = 0; ni < 4; ++ni)
        acc[mi][ni] = __builtin_amdgcn_mfma_f32_16x16x32_bf16(
            af[mi], bfr[ni], acc[mi][ni], 0, 0, 0);
    __syncthreads();
  }
  #pragma unroll
  for (int mi = 0; mi < 4; ++mi) {
    const int rbase = m0 + wm + mi * 16 + quad * 4;
    const int bidx = rbase >> 11;
    const int t0 = rbase & 2047;
    #pragma unroll
    for (int ni = 0; ni < 4; ++ni) {
      const int colC = n0 + wn + ni * 16 + c16;
      if (colC < 2048) {
        #pragma unroll
        for (int r = 0; r < 4; ++r)
          qkb[(size_t)(rbase + r) * 2048 + colC] = f2b(acc[mi][ni][r]);
      } else {
        const int d = colC - 2048;
        const int hh = d >> 6, dd = d & 63;
        ushort4 pk;
        pk.x = f2b(acc[mi][ni][0]); pk.y = f2b(acc[mi][ni][1]);
        pk.z = f2b(acc[mi][ni][2]); pk.w = f2b(acc[mi][ni][3]);
        *(ushort4*)(vtb + (size_t)((bidx * 16 + hh) * 64 + dd) * 2048 + t0) = pk;
      }
    }
  }
}

// -------- proj GEMM: 128x64 tiles, BK=64, XOR swizzle (R8/R9 form) ---------
__global__ __launch_bounds__(256) void gemm_proj(
    const unsigned short* __restrict__ A, const unsigned short* __restrict__ Bt,
    float* __restrict__ C, int M, int N, int K) {
  __shared__ unsigned short As[128 * 64];
  __shared__ unsigned short Bs[64 * 64];
  const int tid = threadIdx.x;
  const int w = tid >> 6, lane = tid & 63;
  const int quad = lane >> 4, c16 = lane & 15;
  const int c7 = c16 & 7;
  const int m0 = blockIdx.y * 128, n0 = blockIdx.x * 64;
  const int wm = (w & 1) * 64, wn = (w >> 1) * 32;
  const int lrow = lane >> 3;
  const int cg = (lane & 7) ^ lrow;
  const unsigned short* ag = A + (size_t)(m0 + w * 32 + lrow) * K + cg * 8;
  const unsigned short* bg = Bt + (size_t)(n0 + w * 16 + lrow) * K + cg * 8;
  f32x4 acc[4][2] = {};
  for (int k0 = 0; k0 < K; k0 += 64) {
    #pragma unroll
    for (int rnd = 0; rnd < 4; ++rnd)
      async16(ag + (size_t)rnd * 8 * K + k0, &As[(w * 32 + rnd * 8) * 64]);
    #pragma unroll
    for (int rnd = 0; rnd < 2; ++rnd)
      async16(bg + (size_t)rnd * 8 * K + k0, &Bs[(w * 16 + rnd * 8) * 64]);
    __syncthreads();
    #pragma unroll
    for (int ks = 0; ks < 2; ++ks) {
      const int gsw = ((ks * 4 + quad) ^ c7) * 8;
      bf16x8 af[4], bfr[2];
      #pragma unroll
      for (int mi = 0; mi < 4; ++mi)
        af[mi] = *(const bf16x8*)&As[(wm + mi * 16 + c16) * 64 + gsw];
      #pragma unroll
      for (int ni = 0; ni < 2; ++ni)
        bfr[ni] = *(const bf16x8*)&Bs[(wn + ni * 16 + c16) * 64 + gsw];
      #pragma unroll
      for (int mi = 0; mi < 4; ++mi)
        #pragma unroll
        for (int ni = 0; ni < 2; ++ni)
          acc[mi][ni] = __builtin_amdgcn_mfma_f32_16x16x32_bf16(
              af[mi], bfr[ni], acc[mi][ni], 0, 0, 0);
    }
    __syncthreads();
  }
  #pragma unroll
  for (int mi = 0; mi < 4; ++mi)
    #pragma unroll
    for (int ni = 0; ni < 2; ++ni) {
      const int colC = n0 + wn + ni * 16 + c16;
      const int rbase = m0 + wm + mi * 16 + quad * 4;
      #pragma unroll
      for (int r = 0; r < 4; ++r)
        C[(size_t)(rbase + r) * N + colC] = acc[mi][ni][r];
    }
}

// -------- flash attention, S^T form, 16 q/wave, 64-q blocks, staged --------
// Grid 1024 blocks (4/CU, LDS exactly 40960B). id&7 = XCD; each XCD owns
// 4 heads x all 32 q-tiles -> per-XCD K/V 2MB (L2-resident re-reads).
__global__ __launch_bounds__(256) void attn_flash(
    const unsigned short* __restrict__ qk,   // [4096][2048]
    const unsigned short* __restrict__ vtg,  // [(b*16+h)*64+d][2048]
    unsigned short* __restrict__ y) {        // [4096][1024]
  __shared__ unsigned short Ks[2][64 * 64];
  __shared__ unsigned short Vs[2][64 * 64];
  __shared__ unsigned short Pt[64 * 64];     // octet-XOR swizzled
  const int tid = threadIdx.x;
  const int w = tid >> 6, lane = tid & 63;
  const int quad = lane >> 4, c16 = lane & 15;
  const int c7 = c16 & 7;
  // XCD head-cluster swizzle: flat id -> (xcd owns heads xcd*4..xcd*4+3)
  const int id = blockIdx.x + 32 * blockIdx.y;   // 0..1023
  const int xcd = id & 7, jj = id >> 3;          // jj: 0..127
  const int by = xcd * 4 + (jj >> 5);            // (b,h) 0..31
  const int bx = jj & 31;                        // q-tile
  const int b = by >> 4, h = by & 15;
  const int i0 = bx * 64;
  const int q0 = i0 + w * 16;                    // wave's 16 q-rows

  bf16x8 qb[2];
  {
    const size_t qr = (size_t)(b * 2048 + q0 + c16) * 2048 + h * 64;
    qb[0] = *(const bf16x8*)(qk + qr + quad * 8);
    qb[1] = *(const bf16x8*)(qk + qr + 32 + quad * 8);
  }
  // ones fragment for the lsum MFMA
  bf16x8 onesf;
  #pragma unroll
  for (int i = 0; i < 8; ++i) onesf[i] = (__bf16)1.0f;

  const int lrow = lane >> 3;
  const int cg = (lane & 7) ^ lrow;
  const int row0 = w * 16 + lrow;
  const int t_start = (i0 >= 512) ? ((i0 - 511) >> 6) : 0;
  const int t_end = (i0 + 63) >> 6;

  const unsigned short* kp0 =
      qk + (size_t)(b * 2048 + t_start * 64 + row0) * 2048 + 1024 + h * 64 + cg * 8;
  const unsigned short* kp1 = kp0 + (size_t)8 * 2048;
  const unsigned short* vp0 =
      vtg + (size_t)((b * 16 + h) * 64 + row0) * 2048 + t_start * 64 + cg * 8;
  const unsigned short* vp1 = vp0 + (size_t)8 * 2048;

  async16(kp0, &Ks[0][(w * 16) * 64]);
  async16(kp1, &Ks[0][(w * 16 + 8) * 64]);
  async16(vp0, &Vs[0][(w * 16) * 64]);
  async16(vp1, &Vs[0][(w * 16 + 8) * 64]);
  kp0 += 131072; kp1 += 131072; vp0 += 64; vp1 += 64;
  __syncthreads();

  f32x4 o[4] = {};
  f32x4 ls = {};
  int cur = 0;

  for (int t = t_start; t <= t_end; ++t) {
    if (t < t_end) {
      unsigned short* kb = &Ks[cur ^ 1][0];
      unsigned short* vb = &Vs[cur ^ 1][0];
      async16(kp0, kb + (w * 16) * 64);
      async16(kp1, kb + (w * 16 + 8) * 64);
      async16(vp0, vb + (w * 16) * 64);
      async16(vp1, vb + (w * 16 + 8) * 64);
      kp0 += 131072; kp1 += 131072; vp0 += 64; vp1 += 64;
    }
    const int kbase = t * 64;
    if (kbase <= q0 + 15 && kbase + 63 >= q0 - 511) {
      const unsigned short* Kc = &Ks[cur][0];
      const unsigned short* Vc = &Vs[cur][0];

      f32x4 s[4] = {};
      #pragma unroll
      for (int nb = 0; nb < 4; ++nb) {
        const int row = nb * 16 + c16;
        bf16x8 a0 = *(const bf16x8*)&Kc[row * 64 + (quad ^ c7) * 8];
        bf16x8 a1 = *(const bf16x8*)&Kc[row * 64 + ((quad + 4) ^ c7) * 8];
        s[nb] = __builtin_amdgcn_mfma_f32_16x16x32_bf16(a0, qb[0], s[nb], 0, 0, 0);
        s[nb] = __builtin_amdgcn_mfma_f32_16x16x32_bf16(a1, qb[1], s[nb], 0, 0, 0);
      }

      const bool full = (kbase + 63 <= q0) && (kbase >= q0 - 496);
      const int iq = q0 + c16;
      const int prow = w * 16 + c16;
      #pragma unroll
      for (int nb = 0; nb < 4; ++nb) {
        ushort4 pk;
        unsigned short* pks = (unsigned short*)&pk;
        #pragma unroll
        for (int r = 0; r < 4; ++r) {
          // scores arrive pre-scaled by 0.125*log2(e) (folded into Q wts)
          float sv = s[nb][r];
          if (!full) {
            const int j = kbase + nb * 16 + quad * 4 + r;
            const bool valid = (j <= iq) && (j >= iq - 511);
            sv = valid ? sv : -3.0e38f;
          }
          const unsigned int pu = __float_as_uint(exp2f(sv)) & 0xffff0000u;
          pks[r] = (unsigned short)(pu >> 16);
        }
        // write octet nb*2+(quad>>1), XOR row&7; 8B half (quad&1)
        *(ushort4*)&Pt[prow * 64 + (((nb * 2 + (quad >> 1)) ^ c7) * 8) +
                       (quad & 1) * 4] = pk;
      }

      #pragma unroll
      for (int ks2 = 0; ks2 < 2; ++ks2) {
        bf16x8 pb = *(const bf16x8*)&Pt[prow * 64 + (((ks2 * 4 + quad) ^ c7) * 8)];
        ls = __builtin_amdgcn_mfma_f32_16x16x32_bf16(onesf, pb, ls, 0, 0, 0);
        #pragma unroll
        for (int nb = 0; nb < 4; ++nb) {
          const int row = nb * 16 + c16;
          bf16x8 va = *(const bf16x8*)&Vc[row * 64 + ((quad + 4 * ks2) ^ c7) * 8];
          o[nb] = __builtin_amdgcn_mfma_f32_16x16x32_bf16(va, pb, o[nb], 0, 0, 0);
        }
      }
    }
    __syncthreads();
    cur ^= 1;
  }

  // ls[r] = sum_k P[k][q=c16] for every r/quad (ones x P) -> no shuffle
  const float inv = 1.0f / ls[0];
  const int iq = q0 + c16;
  #pragma unroll
  for (int nb = 0; nb < 4; ++nb) {
    ushort4 pk;
    unsigned short* pks = (unsigned short*)&pk;
    #pragma unroll
    for (int r = 0; r < 4; ++r) pks[r] = f2b(o[nb][r] * inv);
    *(ushort4*)(y + (size_t)(b * 2048 + iq) * 1024 + h * 64 + nb * 16 + quad * 4) = pk;
  }
}

// ---------------------------------------------------------------------------
extern "C" void kernel_launch(void* const* d_in, const int* in_sizes, int n_in,
                              void* d_out, int out_size, void* d_ws, size_t ws_size,
                              hipStream_t stream) {
  const float* x      = (const float*)d_in[0];  // [4096,1024] fp32
  const float* w_attn = (const float*)d_in[1];  // [1024,3072] fp32
  const float* w_proj = (const float*)d_in[2];  // [1024,1024] fp32
  float* out = (float*)d_out;                   // [4096,1024] fp32

  // ws (bf16 elems): qkb 8M | vtb 4M | wT 3M | pT 1M | xb/y 4M  = 40MB
  unsigned short* qkb = (unsigned short*)d_ws;        // [4096][2048]
  unsigned short* vtb = qkb + (size_t)4096 * 2048;    // [2048][2048]
  unsigned short* wT  = vtb + (size_t)2048 * 2048;    // [3072][1024]
  unsigned short* pT  = wT + (size_t)3072 * 1024;     // [1024][1024]
  unsigned short* xb  = pT + (size_t)1024 * 1024;     // [4096][1024]
  unsigned short* y   = xb;                           // reuse (xb dead post-GEMM1)

  prep<<<dim3(96, 32, 3), 256, 0, stream>>>(x, w_attn, w_proj, xb, wT, pT);

  gemm_qkv<<<dim3(24, 32), 256, 0, stream>>>(xb, wT, qkb, vtb);

  attn_flash<<<dim3(32, 32), 256, 0, stream>>>(qkb, vtb, y);

  gemm_proj<<<dim3(1024 / 64, 4096 / 128), 256, 0, stream>>>(
      y, pT, out, 4096, 1024, 1024);
}

// Round 12
// 91.500 us; speedup vs baseline: 3.2094x; 1.0093x over previous
//
#include <hip/hip_runtime.h>
#include <hip/hip_bf16.h>

// B=2, T=2048, C=1024, H=16, D=64, WINDOW=512. fp32 in/out, bf16 MFMA inside.
// R23: gemm_proj gets the XCD-rectangle swizzle (same verified pattern as
// qkv/attn): 512 blocks -> 8 rectangles of 8m x 8n tiles; per-XCD L2
// footprint A 2MB + B 1MB = 3MB (< 4MB L2). Pure index remap, bijective
// (nwg%8==0), zero regalloc/sync risk. Everything else = R22 (92.35us).
// prep -> gemm_qkv (BK=32 m97) -> attn (16 q/wave, 64-q blocks) -> proj.

typedef __bf16 bf16x8 __attribute__((ext_vector_type(8)));
typedef float f32x4 __attribute__((ext_vector_type(4)));

__device__ __forceinline__ unsigned short f2b(float f) {
  unsigned int u = __float_as_uint(f);
  unsigned int r = (u + 0x7FFFu + ((u >> 16) & 1u)) >> 16;
  return (unsigned short)r;
}
__device__ __forceinline__ void async16(const unsigned short* g,
                                        unsigned short* l) {
  __builtin_amdgcn_global_load_lds(
      (const __attribute__((address_space(1))) unsigned int*)g,
      (__attribute__((address_space(3))) unsigned int*)l, 16, 0, 0);
}

// -------- prep: z=0 cvt x -> xb; z=1/2 transpose+cvt w_attn/w_proj ---------
__global__ __launch_bounds__(256) void prep(
    const float* __restrict__ x, const float* __restrict__ w_attn,
    const float* __restrict__ w_proj, unsigned short* __restrict__ xb,
    unsigned short* __restrict__ wT, unsigned short* __restrict__ pT) {
  __shared__ unsigned short tile[32][33];
  const int z = blockIdx.z;
  if (z == 0) {
    const int id = blockIdx.y * 96 + blockIdx.x;
    if (id >= 2048) return;
    const int i = id * 256 + threadIdx.x;
    const float4 a = ((const float4*)x)[i * 2];
    const float4 b = ((const float4*)x)[i * 2 + 1];
    union { unsigned short us[8]; uint4 v; } t;
    t.us[0] = f2b(a.x); t.us[1] = f2b(a.y); t.us[2] = f2b(a.z); t.us[3] = f2b(a.w);
    t.us[4] = f2b(b.x); t.us[5] = f2b(b.y); t.us[6] = f2b(b.z); t.us[7] = f2b(b.w);
    ((uint4*)xb)[i] = t.v;
    return;
  }
  const float* in = (z == 1) ? w_attn : w_proj;
  unsigned short* out = (z == 1) ? wT : pT;
  const int R = 1024, Cc = (z == 1) ? 3072 : 1024;
  if (blockIdx.x * 32 >= Cc) return;
  const int t = threadIdx.x;
  const int tx = t & 31, ty0 = t >> 5;
  const int c0 = blockIdx.x * 32, r0 = blockIdx.y * 32;
  // Q-weight columns (0..1023 of w_attn) carry the softmax scale so attn's
  // inner loop needs no per-score multiply: 0.125 * log2(e) = 0.18033688.
  const float sc = (z == 1 && (c0 + tx) < 1024) ? 0.18033688f : 1.0f;
  #pragma unroll
  for (int rr = 0; rr < 32; rr += 8)
    tile[ty0 + rr][tx] = f2b(in[(size_t)(r0 + ty0 + rr) * Cc + c0 + tx] * sc);
  __syncthreads();
  #pragma unroll
  for (int rr = 0; rr < 32; rr += 8)
    out[(size_t)(c0 + ty0 + rr) * R + r0 + tx] = tile[tx][ty0 + rr];
}

// -------- qkv GEMM: BK=32 m97 + XOR-4 swizzle + XCD-rectangle map ----------
// R18-verified: VGPR=104, 0 conflicts, ~33.5us. DO NOT perturb the inner
// loop (R19/R20/R21: every graft crossed the 128-VGPR occupancy cliff).
__global__ __launch_bounds__(256) void gemm_qkv(
    const unsigned short* __restrict__ A, const unsigned short* __restrict__ Bt,
    unsigned short* __restrict__ qkb, unsigned short* __restrict__ vtb) {
  const int K = 1024;
  __shared__ unsigned short As[128 * 32];
  __shared__ unsigned short Bs[128 * 32];
  const int tid = threadIdx.x;
  const int w = tid >> 6, lane = tid & 63;
  const int quad = lane >> 4, c16 = lane & 15;
  const int id = blockIdx.x + 24 * blockIdx.y;   // 0..767
  const int xcd = id & 7, j = id >> 3;           // j: 0..95
  const int mt = (xcd & 3) * 8 + (j & 7);        // 0..31
  const int nt = (xcd >> 2) * 12 + (j >> 3);     // 0..23
  const int m0 = mt * 128, n0 = nt * 128;
  const int wm = (w & 1) * 64, wn = (w >> 1) * 64;
  const int srow = w * 16 + (lane >> 2);
  const int scol = ((lane & 3) ^ ((lane >> 2) & 3)) * 8;  // XOR-4 swizzle
  const unsigned short* ag0 = A + (size_t)(m0 + srow) * K + scol;
  const unsigned short* ag1 = A + (size_t)(m0 + 64 + srow) * K + scol;
  const unsigned short* bg0 = Bt + (size_t)(n0 + srow) * K + scol;
  const unsigned short* bg1 = Bt + (size_t)(n0 + 64 + srow) * K + scol;
  const int gsw = (quad ^ (c16 & 3)) * 8;                 // frag-read group
  f32x4 acc[4][4] = {};
  for (int k0 = 0; k0 < K; k0 += 32) {
    async16(ag0 + k0, &As[w * 512]);
    async16(ag1 + k0, &As[w * 512 + 2048]);
    async16(bg0 + k0, &Bs[w * 512]);
    async16(bg1 + k0, &Bs[w * 512 + 2048]);
    __syncthreads();
    bf16x8 af[4], bfr[4];
    #pragma unroll
    for (int mi = 0; mi < 4; ++mi)
      af[mi] = *(const bf16x8*)&As[(wm + mi * 16 + c16) * 32 + gsw];
    #pragma unroll
    for (int ni = 0; ni < 4; ++ni)
      bfr[ni] = *(const bf16x8*)&Bs[(wn + ni * 16 + c16) * 32 + gsw];
    #pragma unroll
    for (int mi = 0; mi < 4; ++mi)
      #pragma unroll
      for (int ni = 0; ni < 4; ++ni)
        acc[mi][ni] = __builtin_amdgcn_mfma_f32_16x16x32_bf16(
            af[mi], bfr[ni], acc[mi][ni], 0, 0, 0);
    __syncthreads();
  }
  #pragma unroll
  for (int mi = 0; mi < 4; ++mi) {
    const int rbase = m0 + wm + mi * 16 + quad * 4;
    const int bidx = rbase >> 11;
    const int t0 = rbase & 2047;
    #pragma unroll
    for (int ni = 0; ni < 4; ++ni) {
      const int colC = n0 + wn + ni * 16 + c16;
      if (colC < 2048) {
        #pragma unroll
        for (int r = 0; r < 4; ++r)
          qkb[(size_t)(rbase + r) * 2048 + colC] = f2b(acc[mi][ni][r]);
      } else {
        const int d = colC - 2048;
        const int hh = d >> 6, dd = d & 63;
        ushort4 pk;
        pk.x = f2b(acc[mi][ni][0]); pk.y = f2b(acc[mi][ni][1]);
        pk.z = f2b(acc[mi][ni][2]); pk.w = f2b(acc[mi][ni][3]);
        *(ushort4*)(vtb + (size_t)((bidx * 16 + hh) * 64 + dd) * 2048 + t0) = pk;
      }
    }
  }
}

// -------- proj GEMM: 128x64 tiles, BK=64, XOR swizzle + XCD rectangles -----
// R23: 512 blocks -> 8 XCD rectangles (8 m-tiles x 8 n-tiles each); per-XCD
// L2 footprint A(y) 2MB + B(pT) 1MB = 3MB. Bijective: id&7 -> xcd, j=id>>3.
__global__ __launch_bounds__(256) void gemm_proj(
    const unsigned short* __restrict__ A, const unsigned short* __restrict__ Bt,
    float* __restrict__ C, int M, int N, int K) {
  __shared__ unsigned short As[128 * 64];
  __shared__ unsigned short Bs[64 * 64];
  const int tid = threadIdx.x;
  const int w = tid >> 6, lane = tid & 63;
  const int quad = lane >> 4, c16 = lane & 15;
  const int c7 = c16 & 7;
  const int id = blockIdx.x + 16 * blockIdx.y;   // 0..511
  const int xcd = id & 7, j = id >> 3;           // j: 0..63
  const int mtile = (xcd & 3) * 8 + (j & 7);     // 0..31
  const int ntile = (xcd >> 2) * 8 + (j >> 3);   // 0..15
  const int m0 = mtile * 128, n0 = ntile * 64;
  const int wm = (w & 1) * 64, wn = (w >> 1) * 32;
  const int lrow = lane >> 3;
  const int cg = (lane & 7) ^ lrow;
  const unsigned short* ag = A + (size_t)(m0 + w * 32 + lrow) * K + cg * 8;
  const unsigned short* bg = Bt + (size_t)(n0 + w * 16 + lrow) * K + cg * 8;
  f32x4 acc[4][2] = {};
  for (int k0 = 0; k0 < K; k0 += 64) {
    #pragma unroll
    for (int rnd = 0; rnd < 4; ++rnd)
      async16(ag + (size_t)rnd * 8 * K + k0, &As[(w * 32 + rnd * 8) * 64]);
    #pragma unroll
    for (int rnd = 0; rnd < 2; ++rnd)
      async16(bg + (size_t)rnd * 8 * K + k0, &Bs[(w * 16 + rnd * 8) * 64]);
    __syncthreads();
    #pragma unroll
    for (int ks = 0; ks < 2; ++ks) {
      const int gsw = ((ks * 4 + quad) ^ c7) * 8;
      bf16x8 af[4], bfr[2];
      #pragma unroll
      for (int mi = 0; mi < 4; ++mi)
        af[mi] = *(const bf16x8*)&As[(wm + mi * 16 + c16) * 64 + gsw];
      #pragma unroll
      for (int ni = 0; ni < 2; ++ni)
        bfr[ni] = *(const bf16x8*)&Bs[(wn + ni * 16 + c16) * 64 + gsw];
      #pragma unroll
      for (int mi = 0; mi < 4; ++mi)
        #pragma unroll
        for (int ni = 0; ni < 2; ++ni)
          acc[mi][ni] = __builtin_amdgcn_mfma_f32_16x16x32_bf16(
              af[mi], bfr[ni], acc[mi][ni], 0, 0, 0);
    }
    __syncthreads();
  }
  #pragma unroll
  for (int mi = 0; mi < 4; ++mi)
    #pragma unroll
    for (int ni = 0; ni < 2; ++ni) {
      const int colC = n0 + wn + ni * 16 + c16;
      const int rbase = m0 + wm + mi * 16 + quad * 4;
      #pragma unroll
      for (int r = 0; r < 4; ++r)
        C[(size_t)(rbase + r) * N + colC] = acc[mi][ni][r];
    }
}

// -------- flash attention, S^T form, 16 q/wave, 64-q blocks, staged --------
// Grid 1024 blocks (4/CU, LDS exactly 40960B). id&7 = XCD; each XCD owns
// 4 heads x all 32 q-tiles -> per-XCD K/V 2MB (L2-resident re-reads).
__global__ __launch_bounds__(256) void attn_flash(
    const unsigned short* __restrict__ qk,   // [4096][2048]
    const unsigned short* __restrict__ vtg,  // [(b*16+h)*64+d][2048]
    unsigned short* __restrict__ y) {        // [4096][1024]
  __shared__ unsigned short Ks[2][64 * 64];
  __shared__ unsigned short Vs[2][64 * 64];
  __shared__ unsigned short Pt[64 * 64];     // octet-XOR swizzled
  const int tid = threadIdx.x;
  const int w = tid >> 6, lane = tid & 63;
  const int quad = lane >> 4, c16 = lane & 15;
  const int c7 = c16 & 7;
  // XCD head-cluster swizzle: flat id -> (xcd owns heads xcd*4..xcd*4+3)
  const int id = blockIdx.x + 32 * blockIdx.y;   // 0..1023
  const int xcd = id & 7, jj = id >> 3;          // jj: 0..127
  const int by = xcd * 4 + (jj >> 5);            // (b,h) 0..31
  const int bx = jj & 31;                        // q-tile
  const int b = by >> 4, h = by & 15;
  const int i0 = bx * 64;
  const int q0 = i0 + w * 16;                    // wave's 16 q-rows

  bf16x8 qb[2];
  {
    const size_t qr = (size_t)(b * 2048 + q0 + c16) * 2048 + h * 64;
    qb[0] = *(const bf16x8*)(qk + qr + quad * 8);
    qb[1] = *(const bf16x8*)(qk + qr + 32 + quad * 8);
  }
  // ones fragment for the lsum MFMA
  bf16x8 onesf;
  #pragma unroll
  for (int i = 0; i < 8; ++i) onesf[i] = (__bf16)1.0f;

  const int lrow = lane >> 3;
  const int cg = (lane & 7) ^ lrow;
  const int row0 = w * 16 + lrow;
  const int t_start = (i0 >= 512) ? ((i0 - 511) >> 6) : 0;
  const int t_end = (i0 + 63) >> 6;

  const unsigned short* kp0 =
      qk + (size_t)(b * 2048 + t_start * 64 + row0) * 2048 + 1024 + h * 64 + cg * 8;
  const unsigned short* kp1 = kp0 + (size_t)8 * 2048;
  const unsigned short* vp0 =
      vtg + (size_t)((b * 16 + h) * 64 + row0) * 2048 + t_start * 64 + cg * 8;
  const unsigned short* vp1 = vp0 + (size_t)8 * 2048;

  async16(kp0, &Ks[0][(w * 16) * 64]);
  async16(kp1, &Ks[0][(w * 16 + 8) * 64]);
  async16(vp0, &Vs[0][(w * 16) * 64]);
  async16(vp1, &Vs[0][(w * 16 + 8) * 64]);
  kp0 += 131072; kp1 += 131072; vp0 += 64; vp1 += 64;
  __syncthreads();

  f32x4 o[4] = {};
  f32x4 ls = {};
  int cur = 0;

  for (int t = t_start; t <= t_end; ++t) {
    if (t < t_end) {
      unsigned short* kb = &Ks[cur ^ 1][0];
      unsigned short* vb = &Vs[cur ^ 1][0];
      async16(kp0, kb + (w * 16) * 64);
      async16(kp1, kb + (w * 16 + 8) * 64);
      async16(vp0, vb + (w * 16) * 64);
      async16(vp1, vb + (w * 16 + 8) * 64);
      kp0 += 131072; kp1 += 131072; vp0 += 64; vp1 += 64;
    }
    const int kbase = t * 64;
    if (kbase <= q0 + 15 && kbase + 63 >= q0 - 511) {
      const unsigned short* Kc = &Ks[cur][0];
      const unsigned short* Vc = &Vs[cur][0];

      f32x4 s[4] = {};
      #pragma unroll
      for (int nb = 0; nb < 4; ++nb) {
        const int row = nb * 16 + c16;
        bf16x8 a0 = *(const bf16x8*)&Kc[row * 64 + (quad ^ c7) * 8];
        bf16x8 a1 = *(const bf16x8*)&Kc[row * 64 + ((quad + 4) ^ c7) * 8];
        s[nb] = __builtin_amdgcn_mfma_f32_16x16x32_bf16(a0, qb[0], s[nb], 0, 0, 0);
        s[nb] = __builtin_amdgcn_mfma_f32_16x16x32_bf16(a1, qb[1], s[nb], 0, 0, 0);
      }

      const bool full = (kbase + 63 <= q0) && (kbase >= q0 - 496);
      const int iq = q0 + c16;
      const int prow = w * 16 + c16;
      #pragma unroll
      for (int nb = 0; nb < 4; ++nb) {
        ushort4 pk;
        unsigned short* pks = (unsigned short*)&pk;
        #pragma unroll
        for (int r = 0; r < 4; ++r) {
          // scores arrive pre-scaled by 0.125*log2(e) (folded into Q wts)
          float sv = s[nb][r];
          if (!full) {
            const int j = kbase + nb * 16 + quad * 4 + r;
            const bool valid = (j <= iq) && (j >= iq - 511);
            sv = valid ? sv : -3.0e38f;
          }
          const unsigned int pu = __float_as_uint(exp2f(sv)) & 0xffff0000u;
          pks[r] = (unsigned short)(pu >> 16);
        }
        // write octet nb*2+(quad>>1), XOR row&7; 8B half (quad&1)
        *(ushort4*)&Pt[prow * 64 + (((nb * 2 + (quad >> 1)) ^ c7) * 8) +
                       (quad & 1) * 4] = pk;
      }

      #pragma unroll
      for (int ks2 = 0; ks2 < 2; ++ks2) {
        bf16x8 pb = *(const bf16x8*)&Pt[prow * 64 + (((ks2 * 4 + quad) ^ c7) * 8)];
        ls = __builtin_amdgcn_mfma_f32_16x16x32_bf16(onesf, pb, ls, 0, 0, 0);
        #pragma unroll
        for (int nb = 0; nb < 4; ++nb) {
          const int row = nb * 16 + c16;
          bf16x8 va = *(const bf16x8*)&Vc[row * 64 + ((quad + 4 * ks2) ^ c7) * 8];
          o[nb] = __builtin_amdgcn_mfma_f32_16x16x32_bf16(va, pb, o[nb], 0, 0, 0);
        }
      }
    }
    __syncthreads();
    cur ^= 1;
  }

  // ls[r] = sum_k P[k][q=c16] for every r/quad (ones x P) -> no shuffle
  const float inv = 1.0f / ls[0];
  const int iq = q0 + c16;
  #pragma unroll
  for (int nb = 0; nb < 4; ++nb) {
    ushort4 pk;
    unsigned short* pks = (unsigned short*)&pk;
    #pragma unroll
    for (int r = 0; r < 4; ++r) pks[r] = f2b(o[nb][r] * inv);
    *(ushort4*)(y + (size_t)(b * 2048 + iq) * 1024 + h * 64 + nb * 16 + quad * 4) = pk;
  }
}

// ---------------------------------------------------------------------------
extern "C" void kernel_launch(void* const* d_in, const int* in_sizes, int n_in,
                              void* d_out, int out_size, void* d_ws, size_t ws_size,
                              hipStream_t stream) {
  const float* x      = (const float*)d_in[0];  // [4096,1024] fp32
  const float* w_attn = (const float*)d_in[1];  // [1024,3072] fp32
  const float* w_proj = (const float*)d_in[2];  // [1024,1024] fp32
  float* out = (float*)d_out;                   // [4096,1024] fp32

  // ws (bf16 elems): qkb 8M | vtb 4M | wT 3M | pT 1M | xb/y 4M  = 40MB
  unsigned short* qkb = (unsigned short*)d_ws;        // [4096][2048]
  unsigned short* vtb = qkb + (size_t)4096 * 2048;    // [2048][2048]
  unsigned short* wT  = vtb + (size_t)2048 * 2048;    // [3072][1024]
  unsigned short* pT  = wT + (size_t)3072 * 1024;     // [1024][1024]
  unsigned short* xb  = pT + (size_t)1024 * 1024;     // [4096][1024]
  unsigned short* y   = xb;                           // reuse (xb dead post-GEMM1)

  prep<<<dim3(96, 32, 3), 256, 0, stream>>>(x, w_attn, w_proj, xb, wT, pT);

  gemm_qkv<<<dim3(24, 32), 256, 0, stream>>>(xb, wT, qkb, vtb);

  attn_flash<<<dim3(32, 32), 256, 0, stream>>>(qkb, vtb, y);

  gemm_proj<<<dim3(1024 / 64, 4096 / 128), 256, 0, stream>>>(
      y, pT, out, 4096, 1024, 1024);
}